// Round 4
// baseline (986.807 us; speedup 1.0000x reference)
//
#include <hip/hip_runtime.h>
#include <math.h>

#define Tt 2048
#define Hh 16
#define Dd 128
#define ATTN 2048

typedef unsigned short u16;
typedef __attribute__((ext_vector_type(8))) short short8;
typedef __attribute__((ext_vector_type(4))) float f32x4;

__device__ __forceinline__ float bf2f(u16 h) {
    union { unsigned int u; float f; } x;
    x.u = ((unsigned int)h) << 16;
    return x.f;
}
// HW bf16 convert (RNE): gfx950 v_cvt_*bf16_f32, 1-2 instr vs 5-op sw RNE
__device__ __forceinline__ u16 f2bf(float f) {
    union { __bf16 b; u16 u; } x;
    x.b = (__bf16)f;
    return x.u;
}
// async global->LDS, 16B per lane; lptr is wave-uniform base, HW adds lane*16.
__device__ __forceinline__ void gl_lds16(const void* g, void* l) {
    __builtin_amdgcn_global_load_lds(
        (const __attribute__((address_space(1))) unsigned int*)g,
        (__attribute__((address_space(3))) unsigned int*)l, 16, 0, 0);
}

// ---- RoPE cos/sin table (reference ignores freqs_cos/sin inputs; recompute).
__global__ __launch_bounds__(256) void freq_kernel(float* __restrict__ cost,
                                                   float* __restrict__ sint) {
    int idx = blockIdx.x * 256 + threadIdx.x;   // Tt*64
    if (idx >= Tt * 64) return;
    int t = idx >> 6, i = idx & 63;
    double inv = exp(-((double)(2 * i) / 128.0) * log(10000.0));
    double ang = (double)t * inv;
    cost[idx] = (float)cos(ang);
    sint[idx] = (float)sin(ang);
}

// ---- fp32 -> bf16 bulk convert (vectorized), n4 = elems/4
__global__ __launch_bounds__(256) void cvt_kernel(const float* __restrict__ in,
                                                  u16* __restrict__ out, int n4) {
    int i = blockIdx.x * 256 + threadIdx.x;
    if (i >= n4) return;
    float4 v = *(const float4*)(in + (size_t)i * 4);
    union { ushort4 u; u16 s[4]; } pk;
    pk.s[0] = f2bf(v.x); pk.s[1] = f2bf(v.y);
    pk.s[2] = f2bf(v.z); pk.s[3] = f2bf(v.w);
    *(ushort4*)(out + (size_t)i * 4) = pk.u;
}

// ---- bf16 MFMA GEMM: C[m,n] = sum_k A[m,k]*W[n,k] + bias[n]
// A: M x 2048 bf16 row-major, W: 2048 x 2048 bf16 row-major (B^T form).
// 128x128 tile, BK=32, 256 thr (4 waves, 2x2 wave grid, 64x64 each).
// MODE 0: fp32 (M,2048). MODE 1: bf16 (B,H,T,D). MODE 2: bf16 (B,H,D,T).
template<int MODE>
__global__ __launch_bounds__(256) void gemm_mfma(const u16* __restrict__ A,
                                                 const u16* __restrict__ W,
                                                 const float* __restrict__ bias,
                                                 void* __restrict__ Cout) {
    __shared__ u16 As[128 * 32];
    __shared__ u16 Ws[128 * 32];
    const int tid  = threadIdx.x;
    const int lane = tid & 63, w = tid >> 6;
    const int l15  = lane & 15, quad = lane >> 4;
    const int wm = w & 1, wn = w >> 1;
    const int m0 = blockIdx.y * 128, n0 = blockIdx.x * 128;

    const f32x4 zero4 = {0.f, 0.f, 0.f, 0.f};
    f32x4 acc[4][4];
#pragma unroll
    for (int mt = 0; mt < 4; mt++)
#pragma unroll
        for (int nt = 0; nt < 4; nt++) acc[mt][nt] = zero4;

    const int srow = w * 32 + (lane >> 2);
    const int scol = (lane & 3) * 8;
    const u16* Ag = A + (size_t)(m0 + srow) * 2048 + scol;
    const u16* Wg = W + (size_t)(n0 + srow) * 2048 + scol;
    u16* AsW = As + w * 1024;
    u16* WsW = Ws + w * 1024;

    for (int k0 = 0; k0 < 2048; k0 += 32) {
        __syncthreads();
        gl_lds16(Ag, AsW);
        gl_lds16(Ag + (size_t)16 * 2048, AsW + 512);
        gl_lds16(Wg, WsW);
        gl_lds16(Wg + (size_t)16 * 2048, WsW + 512);
        Ag += 32; Wg += 32;
        __syncthreads();
        const u16* ar = As + (wm * 64 + l15) * 32 + quad * 8;
        const u16* br = Ws + (wn * 64 + l15) * 32 + quad * 8;
        short8 af[4], bfr[4];
#pragma unroll
        for (int mt = 0; mt < 4; mt++) af[mt] = *(const short8*)(ar + mt * 512);
#pragma unroll
        for (int nt = 0; nt < 4; nt++) bfr[nt] = *(const short8*)(br + nt * 512);
#pragma unroll
        for (int mt = 0; mt < 4; mt++)
#pragma unroll
            for (int nt = 0; nt < 4; nt++)
                acc[mt][nt] = __builtin_amdgcn_mfma_f32_16x16x32_bf16(
                    af[mt], bfr[nt], acc[mt][nt], 0, 0, 0);
    }

    float bn[4];
#pragma unroll
    for (int nt = 0; nt < 4; nt++) bn[nt] = bias[n0 + wn * 64 + nt * 16 + l15];

    if (MODE == 0) {
        float* C = (float*)Cout;
#pragma unroll
        for (int mt = 0; mt < 4; mt++) {
            int m = m0 + wm * 64 + mt * 16 + quad * 4;
#pragma unroll
            for (int nt = 0; nt < 4; nt++) {
                int n = n0 + wn * 64 + nt * 16 + l15;
#pragma unroll
                for (int r = 0; r < 4; r++)
                    C[(size_t)(m + r) * 2048 + n] = acc[mt][nt][r] + bn[nt];
            }
        }
    } else if (MODE == 1) {
        u16* C = (u16*)Cout;
        const int h = n0 >> 7;
#pragma unroll
        for (int mt = 0; mt < 4; mt++) {
            int m = m0 + wm * 64 + mt * 16 + quad * 4;
            int b = m >> 11, t = m & 2047;
            size_t base = ((size_t)(b * Hh + h) * Tt + t) * Dd;
#pragma unroll
            for (int nt = 0; nt < 4; nt++) {
                int d = wn * 64 + nt * 16 + l15;
#pragma unroll
                for (int r = 0; r < 4; r++)
                    C[base + (size_t)r * Dd + d] = f2bf(acc[mt][nt][r] + bn[nt]);
            }
        }
    } else {  // MODE 2: V transposed (B,H,D,T), pack 4 consecutive t per lane
        u16* C = (u16*)Cout;
        const int h = n0 >> 7;
        const int b = m0 >> 11;
        const int tb = (m0 & 2047) + wm * 64;
#pragma unroll
        for (int mt = 0; mt < 4; mt++) {
            int t4 = tb + mt * 16 + quad * 4;
#pragma unroll
            for (int nt = 0; nt < 4; nt++) {
                int d = wn * 64 + nt * 16 + l15;
                union { ushort4 u; u16 s[4]; } pk;
#pragma unroll
                for (int r = 0; r < 4; r++) pk.s[r] = f2bf(acc[mt][nt][r] + bn[nt]);
                *(ushort4*)&C[((size_t)(b * Hh + h) * Dd + d) * Tt + t4] = pk.u;
            }
        }
    }
}

// ---- RoPE in-place on q,k bf16 (B,H,T,D).
// Q additionally pre-scaled by 1/sqrt(D) * log2(e): flash softmax runs in the
// exp2 domain with no per-element scale mul (rotation is linear -> legal fold).
#define QSCALE 0.12751743f
__global__ __launch_bounds__(256) void rope_kernel(u16* __restrict__ q,
                                                   u16* __restrict__ k,
                                                   const float* __restrict__ cost,
                                                   const float* __restrict__ sint) {
    int p = blockIdx.x * 256 + threadIdx.x;    // B*H*T*64 pairs
    int i = p & 63;
    int t = (p >> 6) & 2047;
    float c = cost[t * 64 + i], s = sint[t * 64 + i];
    size_t off = (size_t)p * 2;
    ushort2 qv = *(ushort2*)(q + off);
    float q0 = bf2f(qv.x), q1 = bf2f(qv.y);
    qv.x = f2bf((q0 * c - q1 * s) * QSCALE);
    qv.y = f2bf((q0 * s + q1 * c) * QSCALE);
    *(ushort2*)(q + off) = qv;
    ushort2 kv = *(ushort2*)(k + off);
    float k0 = bf2f(kv.x), k1 = bf2f(kv.y);
    kv.x = f2bf(k0 * c - k1 * s);
    kv.y = f2bf(k0 * s + k1 * c);
    *(ushort2*)(k + off) = kv;
}

// ---- MFMA flash attention (causal), load-balanced pairing + XCD locality:
// grid (64 bh, 8 pair): linear id % 8 == bh % 8 -> all 8 blocks of a bh share
// one XCD's L2. Block handles q-tiles (15-by) then (by): 34 K-iters each.
// K/V staged via REGISTER double-buffer: tile kt+1 loaded to VGPRs during
// compute of kt, ds_write at iter top (global latency off the critical path).
__global__ __launch_bounds__(256) void flash_mfma(const u16* __restrict__ Q,
                                                  const u16* __restrict__ K,
                                                  const u16* __restrict__ Vt,
                                                  u16* __restrict__ O) {
    __shared__ u16 Ks[64 * 128];      // [kp][d], granule-XOR-swizzled by kp&15
    __shared__ u16 Vs[128 * 64];      // [d][kp], granule-XOR-swizzled by d&7
    __shared__ u16 Ps[4][32 * 72];    // per-wave P [q][kp], stride 72
    __shared__ float als[4][32];
    __shared__ float lls[4][32];
    const int tid  = threadIdx.x;
    const int lane = tid & 63, w = tid >> 6;
    const int l15  = lane & 15, quad = lane >> 4;
    const int bh = blockIdx.x, bx = blockIdx.y;

    // per-thread staging addresses (depend only on bh; kt adds an offset)
    const u16* gK[4]; const u16* gV[4];
    u16* KsW[4]; u16* VsW[4];
#pragma unroll
    for (int cc = 0; cc < 4; cc++) {
        int kp = w * 16 + cc * 4 + quad;
        int gs = l15 ^ (cc * 4 + quad);
        gK[cc]  = K + ((size_t)bh * Tt + kp) * Dd + gs * 8;
        KsW[cc] = Ks + (w * 4 + cc) * 512 + lane * 8;
        int d  = w * 32 + cc * 8 + (lane >> 3);
        int gv = (lane & 7) ^ (lane >> 3);
        gV[cc]  = Vt + ((size_t)bh * Dd + d) * Tt + gv * 8;
        VsW[cc] = Vs + (w * 4 + cc) * 512 + lane * 8;
    }

    // prefetch tile 0 into registers
    uint4 kr[4], vr[4];
#pragma unroll
    for (int cc = 0; cc < 4; cc++) kr[cc] = *(const uint4*)(gK[cc]);
#pragma unroll
    for (int cc = 0; cc < 4; cc++) vr[cc] = *(const uint4*)(gV[cc]);

    const f32x4 zero4 = {0.f, 0.f, 0.f, 0.f};

    for (int ph = 0; ph < 2; ph++) {
        const int qt = ph ? bx : 15 - bx;
        const int q0 = qt * 128;

        // Q fragments (B-operand of S^T): q=nt*16+l15, d=ks*32+quad*8
        short8 qf[2][4];
        const u16* Qb = Q + ((size_t)bh * Tt + q0 + w * 32 + l15) * Dd + quad * 8;
#pragma unroll
        for (int nt = 0; nt < 2; nt++)
#pragma unroll
            for (int ks = 0; ks < 4; ks++)
                qf[nt][ks] = *(const short8*)(Qb + nt * 16 * Dd + ks * 32);

        f32x4 Oa[2][8];
#pragma unroll
        for (int mo = 0; mo < 2; mo++)
#pragma unroll
            for (int nt2 = 0; nt2 < 8; nt2++) Oa[mo][nt2] = zero4;
        float mrow[2] = {-INFINITY, -INFINITY};
        float lrow[2] = {0.f, 0.f};

        const int nkt = 2 * qt + 2;
        for (int kt = 0; kt < nkt; kt++) {
            __syncthreads();            // prev iter's LDS reads complete
            // commit current tile (in regs) to LDS
#pragma unroll
            for (int cc = 0; cc < 4; cc++) *(uint4*)KsW[cc] = kr[cc];
#pragma unroll
            for (int cc = 0; cc < 4; cc++) *(uint4*)VsW[cc] = vr[cc];
            // prefetch next tile (next kt, or tile 0 of the next phase)
            const int ktn = (kt + 1 < nkt) ? kt + 1 : 0;
#pragma unroll
            for (int cc = 0; cc < 4; cc++)
                kr[cc] = *(const uint4*)(gK[cc] + (size_t)ktn * 64 * Dd);
#pragma unroll
            for (int cc = 0; cc < 4; cc++)
                vr[cc] = *(const uint4*)(gV[cc] + ktn * 64);
            __syncthreads();

            // wave-level skip: tile fully masked for this wave's 32 q-rows
            if (kt * 64 > q0 + w * 32 + 31) continue;

            // S^T = K * Q^T : rows kp = mt*16+quad*4+r, cols q = nt*16+l15
            f32x4 sc[4][2];
#pragma unroll
            for (int mt = 0; mt < 4; mt++) { sc[mt][0] = zero4; sc[mt][1] = zero4; }
#pragma unroll
            for (int ks = 0; ks < 4; ks++) {
                short8 kf[4];
#pragma unroll
                for (int mt = 0; mt < 4; mt++)
                    kf[mt] = *(const short8*)(Ks + (mt * 16 + l15) * 128 +
                                              (((ks * 4 + quad) ^ l15) * 8));
#pragma unroll
                for (int mt = 0; mt < 4; mt++) {
                    sc[mt][0] = __builtin_amdgcn_mfma_f32_16x16x32_bf16(kf[mt], qf[0][ks], sc[mt][0], 0, 0, 0);
                    sc[mt][1] = __builtin_amdgcn_mfma_f32_16x16x32_bf16(kf[mt], qf[1][ks], sc[mt][1], 0, 0, 0);
                }
            }

            const bool diag = (kt >= 2 * qt);   // only diagonal tiles need mask
            // online softmax in exp2 domain (scale*log2e pre-folded into Q)
#pragma unroll
            for (int nt = 0; nt < 2; nt++) {
                const int q_g = q0 + w * 32 + nt * 16 + l15;
                float sv[16];
#pragma unroll
                for (int mt = 0; mt < 4; mt++)
#pragma unroll
                    for (int r = 0; r < 4; r++)
                        sv[mt * 4 + r] = sc[mt][nt][r];
                if (diag) {
#pragma unroll
                    for (int mt = 0; mt < 4; mt++)
#pragma unroll
                        for (int r = 0; r < 4; r++) {
                            int kp_g = kt * 64 + mt * 16 + quad * 4 + r;
                            if (kp_g > q_g) sv[mt * 4 + r] = -INFINITY;
                        }
                }
                float mx = sv[0];
#pragma unroll
                for (int e = 1; e < 16; e++) mx = fmaxf(mx, sv[e]);
                mx = fmaxf(mx, __shfl_xor(mx, 16, 64));
                mx = fmaxf(mx, __shfl_xor(mx, 32, 64));
                float mnew = fmaxf(mrow[nt], mx);
                float alpha = exp2f(mrow[nt] - mnew);
                float pv[16], rs = 0.f;
#pragma unroll
                for (int e = 0; e < 16; e++) { pv[e] = exp2f(sv[e] - mnew); rs += pv[e]; }
                rs += __shfl_xor(rs, 16, 64);
                rs += __shfl_xor(rs, 32, 64);
                lrow[nt] = lrow[nt] * alpha + rs;
                mrow[nt] = mnew;
                if (quad == 0) als[w][nt * 16 + l15] = alpha;
#pragma unroll
                for (int mt = 0; mt < 4; mt++) {
                    union { ushort4 u; u16 s[4]; } pk;
#pragma unroll
                    for (int r = 0; r < 4; r++) pk.s[r] = f2bf(pv[mt * 4 + r]);
                    *(ushort4*)&Ps[w][(nt * 16 + l15) * 72 + mt * 16 + quad * 4] = pk.u;
                }
            }

            // rescale O by alpha (per O-row q = mo*16+quad*4+r)
            float ao[2][4];
#pragma unroll
            for (int mo = 0; mo < 2; mo++)
#pragma unroll
                for (int r = 0; r < 4; r++) ao[mo][r] = als[w][mo * 16 + quad * 4 + r];
#pragma unroll
            for (int mo = 0; mo < 2; mo++)
#pragma unroll
                for (int nt2 = 0; nt2 < 8; nt2++)
#pragma unroll
                    for (int r = 0; r < 4; r++) Oa[mo][nt2][r] *= ao[mo][r];

            // O += P * V
#pragma unroll
            for (int ks2 = 0; ks2 < 2; ks2++) {
                short8 pf[2];
#pragma unroll
                for (int mo = 0; mo < 2; mo++)
                    pf[mo] = *(const short8*)&Ps[w][(mo * 16 + l15) * 72 + ks2 * 32 + quad * 8];
#pragma unroll
                for (int nt2 = 0; nt2 < 8; nt2++) {
                    short8 vf = *(const short8*)(Vs + (nt2 * 16 + l15) * 64 +
                                                 (((ks2 * 4 + quad) ^ (l15 & 7)) * 8));
                    Oa[0][nt2] = __builtin_amdgcn_mfma_f32_16x16x32_bf16(pf[0], vf, Oa[0][nt2], 0, 0, 0);
                    Oa[1][nt2] = __builtin_amdgcn_mfma_f32_16x16x32_bf16(pf[1], vf, Oa[1][nt2], 0, 0, 0);
                }
            }
        }

        // epilogue: normalize by l, store bf16 (B,T,ATTN)
        if (quad == 0) { lls[w][l15] = lrow[0]; lls[w][16 + l15] = lrow[1]; }
        float li[2][4];
#pragma unroll
        for (int mo = 0; mo < 2; mo++)
#pragma unroll
            for (int r = 0; r < 4; r++) li[mo][r] = 1.f / lls[w][mo * 16 + quad * 4 + r];
        const int b = bh >> 4, h = bh & 15;
#pragma unroll
        for (int mo = 0; mo < 2; mo++)
#pragma unroll
            for (int r = 0; r < 4; r++) {
                size_t ro = ((size_t)b * Tt + q0 + w * 32 + mo * 16 + quad * 4 + r) * ATTN
                            + h * Dd;
#pragma unroll
                for (int nt2 = 0; nt2 < 8; nt2++)
                    O[ro + nt2 * 16 + l15] = f2bf(Oa[mo][nt2][r] * li[mo][r]);
            }
    }
}

extern "C" void kernel_launch(void* const* d_in, const int* in_sizes, int n_in,
                              void* d_out, int out_size, void* d_ws, size_t ws_size,
                              hipStream_t stream) {
    const float* x    = (const float*)d_in[0];
    const float* wq_w = (const float*)d_in[3];
    const float* wq_b = (const float*)d_in[4];
    const float* wk_w = (const float*)d_in[5];
    const float* wk_b = (const float*)d_in[6];
    const float* wv_w = (const float*)d_in[7];
    const float* wv_b = (const float*)d_in[8];
    const float* wo_w = (const float*)d_in[9];
    const float* wo_b = (const float*)d_in[10];

    char* ws = (char*)d_ws;
    u16*   qb  = (u16*)(ws);                    // 32 MiB bf16 (B,H,T,D)
    u16*   kb  = (u16*)(ws + 33554432);         // 32 MiB bf16 (B,H,T,D)
    u16*   vtb = (u16*)(ws + 67108864);         // 32 MiB bf16 (B,H,D,T)
    u16*   xb  = (u16*)(ws + 100663296);        // 32 MiB bf16 x (8192x2048)
    u16*   obb = xb;                            // flash out aliases xb (x dead)
    u16*   wqb = (u16*)(ws + 134217728);        // 8 MiB each
    u16*   wkb = (u16*)(ws + 142606336);
    u16*   wvb = (u16*)(ws + 150994944);
    u16*   wob = (u16*)(ws + 159383552);
    float* ct  = (float*)(ws + 167772160);      // 512 KiB
    float* st  = (float*)(ws + 168296448);      // 512 KiB

    freq_kernel<<<512, 256, 0, stream>>>(ct, st);
    cvt_kernel<<<16384, 256, 0, stream>>>(x, xb, 4194304);
    cvt_kernel<<<4096, 256, 0, stream>>>(wq_w, wqb, 1048576);
    cvt_kernel<<<4096, 256, 0, stream>>>(wk_w, wkb, 1048576);
    cvt_kernel<<<4096, 256, 0, stream>>>(wv_w, wvb, 1048576);
    cvt_kernel<<<4096, 256, 0, stream>>>(wo_w, wob, 1048576);

    dim3 gg(16, 64);
    gemm_mfma<1><<<gg, 256, 0, stream>>>(xb, wqb, wq_b, qb);
    gemm_mfma<1><<<gg, 256, 0, stream>>>(xb, wkb, wk_b, kb);
    gemm_mfma<2><<<gg, 256, 0, stream>>>(xb, wvb, wv_b, vtb);
    rope_kernel<<<32768, 256, 0, stream>>>(qb, kb, ct, st);
    flash_mfma<<<dim3(64, 8), 256, 0, stream>>>(qb, kb, vtb, obb);
    gemm_mfma<0><<<gg, 256, 0, stream>>>(obb, wob, wo_b, (float*)d_out);
}